// Round 12
// baseline (249.089 us; speedup 1.0000x reference)
//
#include <hip/hip_runtime.h>
#include <hip/hip_bf16.h>

// Problem constants
#define NB 4
#define NC 256
#define ND 32
#define WH 1024          // W*H
#define DWH 32768        // D*W*H
#define KTOT 1024        // 4 modalities * 256 channels

typedef __attribute__((ext_vector_type(8))) short short8;
typedef __attribute__((ext_vector_type(4))) float f32x4;

static __device__ __forceinline__ unsigned short f32_to_bf16(float f) {
    unsigned u = __builtin_bit_cast(unsigned, f);
    u = u + 0x7fff + ((u >> 16) & 1);   // round-to-nearest-even
    return (unsigned short)(u >> 16);
}

// HW-packed convert: v_cvt_pk_bf16_f32 (1 instr per pair).
static __device__ __forceinline__ unsigned pack_bf16x2(float lo, float hi) {
    __hip_bfloat162 h = __float22bfloat162_rn(make_float2(lo, hi));
    unsigned u;
    __builtin_memcpy(&u, &h, 4);
    return u;
}

// ---------------------------------------------------------------------------
// Kernel 1: adaptive_avg_pool3d(x,(D,1,1)) == mean over W,H -> pooled[b][c][m][d]
// ~90 us wall (near the 81 us read floor); rocprof-replay inflates it.
// ---------------------------------------------------------------------------
__global__ __launch_bounds__(256) void pool_kernel(
    const float* __restrict__ i0, const float* __restrict__ i1,
    const float* __restrict__ i2, const float* __restrict__ i3,
    float* __restrict__ pooled)
{
    int bid = blockIdx.x;            // (b*NC + c)*4 + m
    int m   = bid & 3;
    int bc  = bid >> 2;              // b*NC + c
    const float* src = (m == 0 ? i0 : m == 1 ? i1 : m == 2 ? i2 : i3)
                       + (size_t)bc * DWH;
    int t = threadIdx.x;
    int d   = t >> 3;                // row 0..31
    int sub = t & 7;                 // 1/8 of the row

    const float4* row = (const float4*)(src + (size_t)d * WH);
    float4 a0 = {0.f, 0.f, 0.f, 0.f}, a1 = {0.f, 0.f, 0.f, 0.f};
    #pragma unroll
    for (int j = 0; j < 16; ++j) {
        float4 u = row[sub + 8 * (2 * j)];
        float4 w = row[sub + 8 * (2 * j + 1)];
        a0.x += u.x; a0.y += u.y; a0.z += u.z; a0.w += u.w;
        a1.x += w.x; a1.y += w.y; a1.z += w.z; a1.w += w.w;
    }
    float s = (a0.x + a0.y) + (a0.z + a0.w) + (a1.x + a1.y) + (a1.z + a1.w);
    s += __shfl_down(s, 4, 64);
    s += __shfl_down(s, 2, 64);
    s += __shfl_down(s, 1, 64);
    if (sub == 0) pooled[bc * 128 + m * 32 + d] = s * (1.0f / 1024.0f);
}

// ---------------------------------------------------------------------------
// Kernel 2: attention weights + effective GEMM A-matrix + effective bias.
// ---------------------------------------------------------------------------
__global__ __launch_bounds__(64) void attn_kernel(
    const float* __restrict__ pooled,
    const float* __restrict__ Wq, const float* __restrict__ bq,
    const float* __restrict__ Wk, const float* __restrict__ bk,
    const float* __restrict__ Wc, const float* __restrict__ bcv,
    unsigned short* __restrict__ Amat, float* __restrict__ beff)
{
    int bc_idx = blockIdx.x;             // b*NC + c
    int lane = threadIdx.x;
    int e = lane & 31;
    const float* P = pooled + bc_idx * 128;

    float q = 0.f, kv[4] = {0.f, 0.f, 0.f, 0.f};
    for (int d = 0; d < 32; ++d) {
        float pq = P[d];
        float wq = Wq[e * 32 + d], wk = Wk[e * 32 + d];
        q += pq * wq;
        #pragma unroll
        for (int m = 0; m < 4; ++m) kv[m] += P[m * 32 + d] * wk;
    }
    q += bq[e];
    #pragma unroll
    for (int m = 0; m < 4; ++m) kv[m] += bk[e];

    float lg[4];
    #pragma unroll
    for (int m = 0; m < 4; ++m) {
        float p = q * kv[m];
        #pragma unroll
        for (int off = 16; off; off >>= 1) p += __shfl_xor(p, off, 32);
        lg[m] = p * 0.17677669529663687f;    // 1/sqrt(32)
    }
    float mx = fmaxf(fmaxf(lg[0], lg[1]), fmaxf(lg[2], lg[3]));
    float ex[4], s = 0.f;
    #pragma unroll
    for (int m = 0; m < 4; ++m) { ex[m] = __expf(lg[m] - mx); s += ex[m]; }
    float a[4];
    #pragma unroll
    for (int m = 0; m < 4; ++m) a[m] = ex[m] / s;

    int c = bc_idx & 255;
    if (lane == 0) {
        float be = 0.f;
        #pragma unroll
        for (int m = 0; m < 4; ++m) be += a[m] * bcv[m * NC + c];
        beff[bc_idx] = be;
    }
    unsigned short* Arow = Amat + (size_t)bc_idx * KTOT;
    #pragma unroll
    for (int j = 0; j < 16; ++j) {
        int k = j * 64 + lane;
        int m = k >> 8, cin = k & 255;
        float v = a[m] * Wc[(m * NC + c) * NC + cin];
        Arow[k] = f32_to_bf16(v);
    }
}

// ---------------------------------------------------------------------------
// Kernel 3: per-batch GEMM. R11 structure + (a) A LDS double-buffer staged
// one iteration ahead (sync2 = vmcnt(12): A(it) covered by a full iter),
// (b) separate B swizzle (chunk ^ (row>>1)&7) killing the 16-way ds_write
// bank conflict (bank = f(chunk) only; one B write spanned 4 chunks).
// ---------------------------------------------------------------------------
#define BM 128
#define BN 128
#define BK 64

static __device__ __forceinline__ int swzA(int row, int chunk) {
    // ushort units: row stride 64 ushorts (=128B), chunk = 8 ushorts (=16B)
    return row * 64 + ((chunk ^ (row & 7)) << 3);
}
static __device__ __forceinline__ int swzB(int row, int chunk) {
    return row * 64 + ((chunk ^ ((row >> 1) & 7)) << 3);
}

__global__ __launch_bounds__(256, 3) void gemm_kernel(
    const float* __restrict__ i0, const float* __restrict__ i1,
    const float* __restrict__ i2, const float* __restrict__ i3,
    const unsigned short* __restrict__ Amat,
    const float* __restrict__ beff,
    float* __restrict__ out)
{
    __shared__ __align__(16) short As[2 * BM * BK];   // 32KB, double-buffered
    __shared__ __align__(16) short Bs[BN * BK];       // 16KB, single-buffered

    // XCD-aware bijective swizzle: 2048 blocks, 8 XCDs, 256 per XCD
    int raw = blockIdx.x;
    int sb  = (raw & 7) * 256 + (raw >> 3);
    int ot = sb & 1;                 // o-tile (fastest -> pairs share B panel)
    int xt = (sb >> 1) & 255;        // x-tile
    int b  = sb >> 9;                // batch
    int o0 = ot * BM, x0 = xt * BN;

    const unsigned short* Ab = Amat + ((size_t)b * NC + o0) * KTOT;

    int t = threadIdx.x;
    int wave = t >> 6, lane = t & 63;
    int wr = wave >> 1, wc = wave & 1;
    int lrow = lane & 15, lk = lane >> 4;

    f32x4 acc[4][4];
    #pragma unroll
    for (int mi = 0; mi < 4; ++mi)
        #pragma unroll
        for (int ni = 0; ni < 4; ++ni)
            acc[mi][ni] = (f32x4){0.f, 0.f, 0.f, 0.f};

    // B staging mapping: thread t loads float4 (4 x's) for 8 consecutive k's.
    int xq = t & 31;                 // x-group (4 floats each)
    int kb = (t >> 5) * 8;           // k base (0..56)

    // A direct-to-LDS mapping: per instr p, wave covers rows wave*32+p*8..+7,
    // lane -> row offset lane>>3, slot lane&7; source chunk pre-swizzled:
    // q = (lane&7) ^ (lane>>3)  (row&7 == lane>>3).
    int ar = wave * 32 + (lane >> 3);
    int aq = (lane & 7) ^ (lane >> 3);
    const unsigned short* asrc = Ab + (size_t)ar * KTOT + aq * 8;

    float4 v[8];

    // ---- prologue: A(0)->As buf0 (4 vmem), B(0)->v (8 vmem) ----
    {
        #pragma unroll
        for (int p = 0; p < 4; ++p)
            __builtin_amdgcn_global_load_lds(
                (const __attribute__((address_space(1))) unsigned int*)
                    (asrc + (size_t)p * 8 * KTOT),
                (__attribute__((address_space(3))) unsigned int*)
                    (As + (wave * 32 + p * 8) * 64),
                16, 0, 0);
        const float* Bb = i0 + (size_t)b * NC * DWH + x0;   // it=0: m=0, cbase=0
        #pragma unroll
        for (int j = 0; j < 8; ++j)
            v[j] = *(const float4*)(Bb + (size_t)(kb + j) * DWH + xq * 4);
    }

    #pragma unroll 1
    for (int it = 0; it < KTOT / BK; ++it) {
        const short* Acur = As + (it & 1) * (BM * BK);
        short* Anx = As + ((it + 1) & 1) * (BM * BK);

        // ---- sync1: previous compute done; Anx/Bs free. Pure wave-sync. ----
        __builtin_amdgcn_s_barrier();
        __builtin_amdgcn_sched_barrier(0);

        // ---- A: async direct-to-LDS for it+1 -> other buffer (4 vmem) ----
        {
            int ja = (it + 1 < 16) ? it + 1 : 15;
            #pragma unroll
            for (int p = 0; p < 4; ++p)
                __builtin_amdgcn_global_load_lds(
                    (const __attribute__((address_space(1))) unsigned int*)
                        (asrc + (size_t)p * 8 * KTOT + ja * BK),
                    (__attribute__((address_space(3))) unsigned int*)
                        (Anx + (wave * 32 + p * 8) * 64),
                    16, 0, 0);
        }
        __builtin_amdgcn_sched_barrier(0);

        // ---- convert v (= B(it), issued a full phase ago) via cvt_pk ----
        uint4 pk[4];
        #pragma unroll
        for (int i = 0; i < 4; ++i) {
            unsigned w[4];
            #pragma unroll
            for (int j = 0; j < 4; ++j)
                w[j] = pack_bf16x2(((const float*)&v[2 * j])[i],
                                   ((const float*)&v[2 * j + 1])[i]);
            pk[i] = (uint4){w[0], w[1], w[2], w[3]};
        }

        // ---- issue B loads for it+1 (8 vmem) ----
        {
            int itn = (it < 15) ? it + 1 : 15;
            int m = itn >> 2, cbase = (itn & 3) * 64;
            const float* Bb = (m == 0 ? i0 : m == 1 ? i1 : m == 2 ? i2 : i3)
                              + ((size_t)b * NC + cbase) * DWH + x0;
            #pragma unroll
            for (int j = 0; j < 8; ++j)
                v[j] = *(const float4*)(Bb + (size_t)(kb + j) * DWH + xq * 4);
        }
        __builtin_amdgcn_sched_barrier(0);

        // ---- write converted B(it) -> Bs (swzB: conflict-free) ----
        #pragma unroll
        for (int i = 0; i < 4; ++i)
            *(uint4*)(&Bs[swzB(xq * 4 + i, t >> 5)]) = pk[i];

        // ---- sync2: drain A(it) (12 newer ops: B(it+1):8 + A(it+1):4);
        //      ds_writes visible; A(it+1), B(it+1) stay in flight ----
        asm volatile("s_waitcnt vmcnt(12) lgkmcnt(0)" ::: "memory");
        __builtin_amdgcn_s_barrier();
        __builtin_amdgcn_sched_barrier(0);

        // ---- compute on Acur / Bs: 2 K-halves of 32 ----
        #pragma unroll
        for (int kk = 0; kk < 2; ++kk) {
            int q = kk * 4 + lk;
            short8 af[4], bf[4];
            #pragma unroll
            for (int mi = 0; mi < 4; ++mi) {
                int r = wr * 64 + mi * 16 + lrow;
                af[mi] = *(const short8*)(&Acur[swzA(r, q)]);
            }
            #pragma unroll
            for (int ni = 0; ni < 4; ++ni) {
                int x = wc * 64 + ni * 16 + lrow;
                bf[ni] = *(const short8*)(&Bs[swzB(x, q)]);
            }
            __builtin_amdgcn_s_setprio(1);
            #pragma unroll
            for (int mi = 0; mi < 4; ++mi)
                #pragma unroll
                for (int ni = 0; ni < 4; ++ni)
                    acc[mi][ni] = __builtin_amdgcn_mfma_f32_16x16x32_bf16(
                        af[mi], bf[ni], acc[mi][ni], 0, 0, 0);
            __builtin_amdgcn_s_setprio(0);
        }
    }

    // ---- epilogue: add bias, store fp32 ----
    // C/D layout (16x16x32): col = lane&15, row = (lane>>4)*4 + reg
    const float* beff_b = beff + b * NC + o0;
    float* outb = out + ((size_t)b * NC + o0) * DWH + x0;
    #pragma unroll
    for (int mi = 0; mi < 4; ++mi) {
        #pragma unroll
        for (int r4 = 0; r4 < 4; ++r4) {
            int row = wr * 64 + mi * 16 + lk * 4 + r4;
            float bias = beff_b[row];
            float* orow = outb + (size_t)row * DWH;
            #pragma unroll
            for (int ni = 0; ni < 4; ++ni) {
                int col = wc * 64 + ni * 16 + lrow;
                orow[col] = acc[mi][ni][r4] + bias;
            }
        }
    }
}

// ---------------------------------------------------------------------------
extern "C" void kernel_launch(void* const* d_in, const int* in_sizes, int n_in,
                              void* d_out, int out_size, void* d_ws, size_t ws_size,
                              hipStream_t stream) {
    const float* m1 = (const float*)d_in[0];
    const float* m2 = (const float*)d_in[1];
    const float* m3 = (const float*)d_in[2];
    const float* m4 = (const float*)d_in[3];
    const float* Wq = (const float*)d_in[4];
    const float* bq = (const float*)d_in[5];
    const float* Wk = (const float*)d_in[6];
    const float* bk = (const float*)d_in[7];
    const float* Wc = (const float*)d_in[8];
    const float* bcv = (const float*)d_in[9];
    float* out = (float*)d_out;

    float* pooled        = (float*)d_ws;                                // 512 KB
    unsigned short* Amat = (unsigned short*)((char*)d_ws + 524288);     // 2 MB
    float* beff          = (float*)((char*)d_ws + 524288 + 2097152);    // 4 KB

    pool_kernel<<<NB * NC * 4, 256, 0, stream>>>(m1, m2, m3, m4, pooled);
    attn_kernel<<<NB * NC, 64, 0, stream>>>(pooled, Wq, bq, Wk, bk, Wc, bcv,
                                            Amat, beff);
    gemm_kernel<<<(NB) * (NC / BM) * (DWH / BN), 256, 0, stream>>>(
        m1, m2, m3, m4, Amat, beff, out);
}